// Round 13
// baseline (32.080 us; speedup 1.0000x reference)
//
#include <hip/hip_runtime.h>
#include <hip/hip_bf16.h>

#define GG    96     // grid size
#define DD    128    // feature dim
#define KC    32     // K-chunk = MFMA K
#define APAD  40     // padded LDS row stride in ushorts (80 B)
#define RCUT  18     // gaussian support radius in rows (exp(-18^2/32)=4e-5; validated R10/R12)
#define NPER  512    // nodes per batch (N/B)
#define NPB   8      // nodes per preprocess block (512 blocks = 2/CU for TLP)

typedef __attribute__((ext_vector_type(8))) short short8v;  // 8 bf16 = 4 VGPRs
typedef __attribute__((ext_vector_type(4))) float f32x4;    // MFMA acc

// ---------------- Kernel 1: preprocess = sort + (py,px,g) table + fT transpose ----------------
__global__ __launch_bounds__(256) void preprocess(
    const float* __restrict__ pos, const float* __restrict__ log_sigma,
    const float* __restrict__ f,
    int* __restrict__ pref, float4* __restrict__ tab,
    unsigned short* __restrict__ fTh, unsigned short* __restrict__ fTl,
    int Nn)
{
    const int blk   = (int)blockIdx.x;
    const int bpb   = NPER / NPB;             // 64 blocks per batch
    const int b     = blk / bpb;
    const int j0loc = (blk % bpb) * NPB;
    const int nbase = b * NPER;
    const int t     = (int)threadIdx.x;
    const int w     = t >> 6, lane = t & 63;

    __shared__ int ghist[8][GG];
    __shared__ int gpart[8][GG];
    __shared__ int spre[GG + 1];
    __shared__ int inv[NPER];
    __shared__ int sn[NPB];
    __shared__ int wtot;
    __shared__ float spy[NPB], spx[NPB];
    __shared__ float sPy[32][NPB], sPx[32][NPB];
    __shared__ __align__(16) float sT[DD][9];   // transpose staging [128][9]

    // ---- (a) in-LDS counting sort of the whole batch (redundant per block) ----
    for (int i = t; i < 8 * GG; i += 256) (&ghist[0][0])[i] = 0;
    __syncthreads();

    int binA, binB;
    {
        float pyA = pos[(size_t)(nbase + t) * 2];
        float pyB = pos[(size_t)(nbase + t + 256) * 2];
        binA = (int)floorf(pyA); binA = binA < 0 ? 0 : (binA > GG - 1 ? GG - 1 : binA);
        binB = (int)floorf(pyB); binB = binB < 0 ? 0 : (binB > GG - 1 ? GG - 1 : binB);
        atomicAdd(&ghist[w][binA], 1);
        atomicAdd(&ghist[4 + w][binB], 1);
    }
    const unsigned long long below = (lane == 0) ? 0ull : (~0ull >> (64 - lane));
    unsigned long long mA = ~0ull, mB = ~0ull;
#pragma unroll
    for (int bit = 0; bit < 7; ++bit) {
        unsigned long long bA = __ballot((binA >> bit) & 1);
        unsigned long long bB = __ballot((binB >> bit) & 1);
        mA &= ((binA >> bit) & 1) ? bA : ~bA;
        mB &= ((binB >> bit) & 1) ? bB : ~bB;
    }
    const int rA = __popcll(mA & below);
    const int rB = __popcll(mB & below);
    __syncthreads();

    int bc = 0;
    if (t < GG) {
        int s = 0;
#pragma unroll
        for (int g = 0; g < 8; ++g) { gpart[g][t] = s; s += ghist[g][t]; }
        bc = s;
    }
    // two-wave Kogge-Stone inclusive scan over the 96 bin counts
    int xs = bc;
#pragma unroll
    for (int off = 1; off < 64; off <<= 1) {
        int v = __shfl_up(xs, off, 64);
        if (lane >= off) xs += v;
    }
    if (t == 63) wtot = xs;
    __syncthreads();
    if (t >= 64 && t < GG) xs += wtot;
    if (t < GG) spre[t + 1] = xs;
    if (t == 0) spre[0] = 0;
    __syncthreads();

    inv[spre[binA] + gpart[w][binA] + rA]     = t;
    inv[spre[binB] + gpart[4 + w][binB] + rB] = t + 256;
    if (j0loc == 0 && t < GG + 1) pref[b * (GG + 1) + t] = spre[t];
    __syncthreads();

    if (t < NPB) {
        int nl = inv[j0loc + t];
        sn[t]  = nl;
        spy[t] = pos[(size_t)(nbase + nl) * 2 + 0];
        spx[t] = pos[(size_t)(nbase + nl) * 2 + 1];
    }
    __syncthreads();

    // ---- (b) per-node normalizer g = 1/(Sy*Sx+1e-8) -> table (py,px,g) ----
    const int g = t >> 3, c = t & 7;          // g: 32 y-groups, c: node
    const float sig = expf(log_sigma[0]);
    const float inv2s2 = 1.0f / (2.0f * sig * sig);
    const float py = spy[c], px = spx[c];

    float pey = 0.f, pex = 0.f;
#pragma unroll
    for (int r = 0; r < 3; ++r) {
        int yy = r * 32 + g;
        float dy = (float)yy - py;
        float dx = (float)yy - px;
        pey += expf(-dy * dy * inv2s2);
        pex += expf(-dx * dx * inv2s2);
    }
    sPy[g][c] = pey; sPx[g][c] = pex;
    __syncthreads();

    const int jcol = nbase + j0loc;
    if (t < NPB) {
        float sy = 0.f, sx = 0.f;
#pragma unroll
        for (int gg = 0; gg < 32; ++gg) { sy += sPy[gg][t]; sx += sPx[gg][t]; }
        float gf = 1.0f / (sy * sx + 1e-8f);
        tab[jcol + t] = make_float4(spy[t], spx[t], gf, 0.0f);
    }

    // ---- (c) gather-transpose-split f -> bf16 hi/lo ----
    {
        int nl  = t >> 5;                     // 0..7
        int cc  = t & 31;                     // float4 column
        float4 v = *(const float4*)(f + (size_t)(nbase + sn[nl]) * DD + cc * 4);
        sT[cc * 4 + 0][nl] = v.x;
        sT[cc * 4 + 1][nl] = v.y;
        sT[cc * 4 + 2][nl] = v.z;
        sT[cc * 4 + 3][nl] = v.w;
    }
    __syncthreads();

    const int d = t >> 1, h = t & 1;          // d row, 4-node half
    unsigned int ph[2], pl[2];
#pragma unroll
    for (int q = 0; q < 2; ++q) {
        float x0 = sT[d][h * 4 + 2 * q];
        float x1 = sT[d][h * 4 + 2 * q + 1];
        __hip_bfloat16 h0 = __float2bfloat16(x0);
        __hip_bfloat16 h1 = __float2bfloat16(x1);
        __hip_bfloat16 l0 = __float2bfloat16(x0 - __bfloat162float(h0));
        __hip_bfloat16 l1 = __float2bfloat16(x1 - __bfloat162float(h1));
        unsigned short uh0 = *(const unsigned short*)&h0;
        unsigned short uh1 = *(const unsigned short*)&h1;
        unsigned short ul0 = *(const unsigned short*)&l0;
        unsigned short ul1 = *(const unsigned short*)&l1;
        ph[q] = (unsigned int)uh0 | ((unsigned int)uh1 << 16);
        pl[q] = (unsigned int)ul0 | ((unsigned int)ul1 << 16);
    }
    *(int2*)(fTh + (size_t)d * Nn + jcol + h * 4) = make_int2((int)ph[0], (int)ph[1]);
    *(int2*)(fTl + (size_t)d * Nn + jcol + h * 4) = make_int2((int)pl[0], (int)pl[1]);
}

// ---------------- Kernel 2: MFMA splat GEMM; W generated on the fly from (py,px,g) ----------------
__global__ __launch_bounds__(256, 3) void splat_mfma(
    const unsigned short* __restrict__ fTh, const unsigned short* __restrict__ fTl,
    const float4* __restrict__ tab, const float* __restrict__ log_sigma,
    const int* __restrict__ pref,
    float* __restrict__ out, int Nn, int n_per)
{
    // XCD-chunked swizzle: XCD x owns batch x (y-major within batch).
    const int swz = ((int)blockIdx.x % 8) * GG + (int)blockIdx.x / 8;
    const int b = swz / GG;
    const int y = swz % GG;
    const int tid = (int)threadIdx.x;
    const int lane = tid & 63;
    const int wid  = tid >> 6;
    const int lr = lane & 15;
    const int kg = lane >> 4;
    const int kpw = tid & 15;                 // fixed k-pair per thread (256 % 16 == 0)
    const float yf = (float)y;

    const float sig = expf(log_sigma[0]);
    const float inv2s2 = 1.0f / (2.0f * sig * sig);

    __shared__ __align__(16) unsigned short sW[2][GG][APAD];  // 15 KiB dbuf

    f32x4 acc[2][6];
#pragma unroll
    for (int mi = 0; mi < 2; ++mi)
#pragma unroll
        for (int ni = 0; ni < 6; ++ni) acc[mi][ni] = (f32x4){0.f, 0.f, 0.f, 0.f};

    const int lob = y - RCUT < 0 ? 0 : y - RCUT;
    const int hib = y + RCUT > GG ? GG : y + RCUT;
    const int klo = pref[b * (GG + 1) + lob];
    const int khi = pref[b * (GG + 1) + hib];
    const int c0 = klo >> 5;
    const int c1 = (khi + 31) >> 5;

    const int nbase = b * n_per;

    const int ar0 = wid * 32 + lr;
    const unsigned short* pH0 = fTh + (size_t)ar0 * Nn;
    const unsigned short* pH1 = fTh + (size_t)(ar0 + 16) * Nn;
    const unsigned short* pL0 = fTl + (size_t)ar0 * Nn;
    const unsigned short* pL1 = fTl + (size_t)(ar0 + 16) * Nn;

// W tile on the fly: w[n,(y,x)] = (exp(-(y-py)^2 a)*g) * exp(-(x-px)^2 a)
#define WGEN(CC, BUF)                                                              \
    {                                                                              \
        const int ncur_ = nbase + (CC) * KC;                                       \
        const float4 t0_ = tab[ncur_ + 2 * kpw];                                   \
        const float4 t1_ = tab[ncur_ + 2 * kpw + 1];                               \
        const float dy0_ = yf - t0_.x, dy1_ = yf - t1_.x;                          \
        const float ey0_ = expf(-dy0_ * dy0_ * inv2s2) * t0_.z;                    \
        const float ey1_ = expf(-dy1_ * dy1_ * inv2s2) * t1_.z;                    \
        _Pragma("unroll")                                                          \
        for (int i_ = 0; i_ < 6; ++i_) {                                           \
            int x_  = (tid + 256 * i_) >> 4;                                       \
            float xf_ = (float)x_;                                                 \
            float dx0_ = xf_ - t0_.y, dx1_ = xf_ - t1_.y;                          \
            float w0_ = ey0_ * expf(-dx0_ * dx0_ * inv2s2);                        \
            float w1_ = ey1_ * expf(-dx1_ * dx1_ * inv2s2);                        \
            __hip_bfloat162 bb_ = __float22bfloat162_rn(make_float2(w0_, w1_));    \
            *(unsigned int*)&sW[BUF][x_][2 * kpw] = *(unsigned int*)&bb_;          \
        }                                                                          \
    }

    if (c0 < c1) WGEN(c0, 0);
    __syncthreads();

    int cur = 0;
    for (int c = c0; c < c1; ++c) {
        const int k0 = nbase + c * KC + kg * 8;
        short8v cah0 = *(const short8v*)(pH0 + k0);
        short8v cah1 = *(const short8v*)(pH1 + k0);
        short8v cal0 = *(const short8v*)(pL0 + k0);
        short8v cal1 = *(const short8v*)(pL1 + k0);

        if (c + 1 < c1) WGEN(c + 1, cur ^ 1);

#pragma unroll
        for (int ni = 0; ni < 6; ++ni) {
            short8v bv = *(const short8v*)&sW[cur][ni * 16 + lr][kg * 8];
            acc[0][ni] = __builtin_amdgcn_mfma_f32_16x16x32_bf16(cah0, bv, acc[0][ni], 0, 0, 0);
            acc[1][ni] = __builtin_amdgcn_mfma_f32_16x16x32_bf16(cah1, bv, acc[1][ni], 0, 0, 0);
            acc[0][ni] = __builtin_amdgcn_mfma_f32_16x16x32_bf16(cal0, bv, acc[0][ni], 0, 0, 0);
            acc[1][ni] = __builtin_amdgcn_mfma_f32_16x16x32_bf16(cal1, bv, acc[1][ni], 0, 0, 0);
        }
        __syncthreads();
        cur ^= 1;
    }

    // nt epilogue (R8-validated form)
#pragma unroll
    for (int mi = 0; mi < 2; ++mi)
#pragma unroll
        for (int ni = 0; ni < 6; ++ni) {
            const int d0 = wid * 32 + mi * 16 + kg * 4;
            const int x  = ni * 16 + lr;
            float* op = out + (((size_t)b * DD + d0) * GG + y) * GG + x;
#pragma unroll
            for (int r = 0; r < 4; ++r)
                __builtin_nontemporal_store(acc[mi][ni][r], op + (size_t)r * GG * GG);
        }
#undef WGEN
}

extern "C" void kernel_launch(void* const* d_in, const int* in_sizes, int n_in,
                              void* d_out, int out_size, void* d_ws, size_t ws_size,
                              hipStream_t stream) {
    const float* feat = (const float*)d_in[0];
    const float* pos  = (const float*)d_in[1];
    const float* lsig = (const float*)d_in[4];

    const int N  = in_sizes[2];                        // 4096
    const int B  = out_size / (DD * GG * GG);          // 8
    const int n_per = N / B;                           // 512 (== NPER)

    int* pref = (int*)d_ws;                            // B x 97 ints (3104 B, 16B-mult)
    float4* tab = (float4*)(pref + B * (GG + 1));      // N x float4 (py,px,g,0)
    unsigned short* fTh = (unsigned short*)(tab + N);  // 128 x N bf16
    unsigned short* fTl = fTh + (size_t)DD * N;        // 128 x N bf16

    preprocess<<<N / NPB, 256, 0, stream>>>(pos, lsig, feat, pref, tab, fTh, fTl, N);

    splat_mfma<<<B * GG, 256, 0, stream>>>(fTh, fTl, tab, lsig, pref, (float*)d_out, N, n_per);
}

// Round 14
// 26.248 us; speedup vs baseline: 1.2222x; 1.2222x over previous
//
#include <hip/hip_runtime.h>
#include <hip/hip_bf16.h>

#define GG    96     // grid size
#define DD    128    // feature dim
#define KC    32     // K-chunk = MFMA K
#define APAD  40     // padded LDS row stride in ushorts (80 B)
#define RCUT  18     // gaussian support radius in rows (exp(-18^2/32)=4e-5; validated)
#define NWIN  18     // normalizer-sum window radius (same cutoff scale)
#define NPER  512    // nodes per batch (N/B)

typedef __attribute__((ext_vector_type(8))) short short8v;  // 8 bf16 = 4 VGPRs
typedef __attribute__((ext_vector_type(4))) float f32x4;    // MFMA acc

// Single fused kernel: each (b,y) block is fully self-sufficient.
//  (a) ballot counting-sort of its batch by floor(py)  (validated R6/R8 logic)
//  (b) windowed normalizers (py,px,g) for its chunk-aligned K-band
//  (c) MFMA K-loop: W on the fly; A gathered directly from f (f32) with
//      in-register bf16 hi/lo split (bit-identical to the old fT path)
__global__ __launch_bounds__(256, 3) void splat_all(
    const float* __restrict__ f, const float* __restrict__ pos,
    const float* __restrict__ log_sigma, float* __restrict__ out,
    int Nn, int n_per)
{
    // XCD-chunked swizzle: XCD x owns batch x (y-major within batch).
    const int swz = ((int)blockIdx.x % 8) * GG + (int)blockIdx.x / 8;
    const int b = swz / GG;
    const int y = swz % GG;
    const int tid = (int)threadIdx.x;
    const int lane = tid & 63;
    const int wvid = tid >> 6;
    const int lr = lane & 15;
    const int kg = lane >> 4;
    const int kpw = tid & 15;                 // fixed k-pair per thread
    const int nbase = b * NPER;
    const float yf = (float)y;

    __shared__ int ghist[8][GG];
    __shared__ int gpart[8][GG];
    __shared__ int spre[GG + 1];
    __shared__ int inv[NPER];
    __shared__ int wtot;
    __shared__ float spy_s[NPER], spx_s[NPER], sg_s[NPER];
    __shared__ float tSy[NPER], tSx[NPER];
    __shared__ __align__(16) unsigned short sW[2][GG][APAD];  // 15 KiB dbuf

    // ---- (a) in-LDS counting sort of the batch ----
    for (int i = tid; i < 8 * GG; i += 256) (&ghist[0][0])[i] = 0;
    __syncthreads();

    int binA, binB;
    {
        float pyA = pos[(size_t)(nbase + tid) * 2];
        float pyB = pos[(size_t)(nbase + tid + 256) * 2];
        binA = (int)floorf(pyA); binA = binA < 0 ? 0 : (binA > GG - 1 ? GG - 1 : binA);
        binB = (int)floorf(pyB); binB = binB < 0 ? 0 : (binB > GG - 1 ? GG - 1 : binB);
        atomicAdd(&ghist[wvid][binA], 1);
        atomicAdd(&ghist[4 + wvid][binB], 1);
    }
    const unsigned long long below = (lane == 0) ? 0ull : (~0ull >> (64 - lane));
    unsigned long long mA = ~0ull, mB = ~0ull;
#pragma unroll
    for (int bit = 0; bit < 7; ++bit) {
        unsigned long long bA = __ballot((binA >> bit) & 1);
        unsigned long long bB = __ballot((binB >> bit) & 1);
        mA &= ((binA >> bit) & 1) ? bA : ~bA;
        mB &= ((binB >> bit) & 1) ? bB : ~bB;
    }
    const int rA = __popcll(mA & below);
    const int rB = __popcll(mB & below);
    __syncthreads();

    int bc = 0;
    if (tid < GG) {
        int s = 0;
#pragma unroll
        for (int g = 0; g < 8; ++g) { gpart[g][tid] = s; s += ghist[g][tid]; }
        bc = s;
    }
    int xs = bc;
#pragma unroll
    for (int off = 1; off < 64; off <<= 1) {
        int v = __shfl_up(xs, off, 64);
        if (lane >= off) xs += v;
    }
    if (tid == 63) wtot = xs;
    __syncthreads();
    if (tid >= 64 && tid < GG) xs += wtot;
    if (tid < GG) spre[tid + 1] = xs;
    if (tid == 0) spre[0] = 0;
    __syncthreads();

    inv[spre[binA] + gpart[wvid][binA] + rA]     = tid;
    inv[spre[binB] + gpart[4 + wvid][binB] + rB] = tid + 256;
    __syncthreads();

    // ---- band bounds (chunk-aligned) ----
    const int lob = y - RCUT < 0 ? 0 : y - RCUT;
    const int hib = y + RCUT > GG ? GG : y + RCUT;
    const int klo = spre[lob];
    const int khi = spre[hib];
    const int c0 = klo >> 5;
    const int c1 = (khi + 31) >> 5;
    const int jlo = c0 * KC, jhi = c1 * KC;
    const int nb = jhi - jlo;

    // ---- (b) per-node (py,px,g) for the band ----
    for (int i = tid; i < nb; i += 256) {
        int j = jlo + i, nl = inv[j];
        spy_s[j] = pos[(size_t)(nbase + nl) * 2 + 0];
        spx_s[j] = pos[(size_t)(nbase + nl) * 2 + 1];
    }
    __syncthreads();

    const float sig = expf(log_sigma[0]);
    const float inv2s2 = 1.0f / (2.0f * sig * sig);

    for (int i = tid; i < 2 * nb; i += 256) {
        int j = jlo + (i >> 1);
        float p = (i & 1) ? spx_s[j] : spy_s[j];
        int fp = (int)floorf(p);
        int w0 = fp - (NWIN - 1); if (w0 < 0) w0 = 0;
        int w1 = fp + NWIN;       if (w1 > GG - 1) w1 = GG - 1;
        float s = 0.f;
        for (int yy = w0; yy <= w1; ++yy) {
            float d = (float)yy - p;
            s += __expf(-d * d * inv2s2);
        }
        if (i & 1) tSx[j] = s; else tSy[j] = s;
    }
    __syncthreads();
    for (int i = tid; i < nb; i += 256) {
        int j = jlo + i;
        sg_s[j] = 1.0f / (tSy[j] * tSx[j] + 1e-8f);
    }
    __syncthreads();

    // ---- (c) K-loop ----
    f32x4 acc[2][6];
#pragma unroll
    for (int mi = 0; mi < 2; ++mi)
#pragma unroll
        for (int ni = 0; ni < 6; ++ni) acc[mi][ni] = (f32x4){0.f, 0.f, 0.f, 0.f};

    const int ar0 = wvid * 32 + lr;
    const float* fcol = f + (size_t)nbase * DD + ar0;   // + nl*DD (+16 for row2)

#define WGEN(CC, BUF)                                                              \
    {                                                                              \
        const int j0_ = (CC) * KC + 2 * kpw;                                       \
        const float py0_ = spy_s[j0_], py1_ = spy_s[j0_ + 1];                      \
        const float px0_ = spx_s[j0_], px1_ = spx_s[j0_ + 1];                      \
        const float g0_ = sg_s[j0_],  g1_ = sg_s[j0_ + 1];                         \
        const float dy0_ = yf - py0_, dy1_ = yf - py1_;                            \
        const float ey0_ = __expf(-dy0_ * dy0_ * inv2s2) * g0_;                    \
        const float ey1_ = __expf(-dy1_ * dy1_ * inv2s2) * g1_;                    \
        _Pragma("unroll")                                                          \
        for (int i_ = 0; i_ < 6; ++i_) {                                           \
            int x_  = (tid + 256 * i_) >> 4;                                       \
            float xf_ = (float)x_;                                                 \
            float dx0_ = xf_ - px0_, dx1_ = xf_ - px1_;                            \
            float w0_ = ey0_ * __expf(-dx0_ * dx0_ * inv2s2);                      \
            float w1_ = ey1_ * __expf(-dx1_ * dx1_ * inv2s2);                      \
            __hip_bfloat162 bb_ = __float22bfloat162_rn(make_float2(w0_, w1_));    \
            *(unsigned int*)&sW[BUF][x_][2 * kpw] = *(unsigned int*)&bb_;          \
        }                                                                          \
    }

// pack pair (x0,x1) -> hi u32 (2 bf16) and lo u32 (2 bf16 of residual)
#define PKPAIR(X0, X1, HI, LO)                                                     \
    {                                                                              \
        __hip_bfloat162 h_ = __float22bfloat162_rn(make_float2((X0), (X1)));       \
        unsigned int hu_; __builtin_memcpy(&hu_, &h_, 4);                          \
        unsigned int b0_ = hu_ << 16, b1_ = hu_ & 0xFFFF0000u;                     \
        float h0_, h1_;                                                            \
        __builtin_memcpy(&h0_, &b0_, 4);                                           \
        __builtin_memcpy(&h1_, &b1_, 4);                                           \
        __hip_bfloat162 l_ = __float22bfloat162_rn(                                \
            make_float2((X0) - h0_, (X1) - h1_));                                  \
        (HI) = hu_; __builtin_memcpy(&(LO), &l_, 4);                               \
    }

    if (c0 < c1) WGEN(c0, 0);
    __syncthreads();

    int cur = 0;
    for (int c = c0; c < c1; ++c) {
        // A gather: orig node ids for my kg's 8 k's, then 16 direct f32 loads.
        // Lanes lr=0..15 read consecutive d -> full 64B segments (L2-hot).
        int4 iv0 = *(const int4*)&inv[c * KC + kg * 8];
        int4 iv1 = *(const int4*)&inv[c * KC + kg * 8 + 4];
        float v00 = fcol[(size_t)iv0.x * DD],      v01 = fcol[(size_t)iv0.y * DD];
        float v02 = fcol[(size_t)iv0.z * DD],      v03 = fcol[(size_t)iv0.w * DD];
        float v04 = fcol[(size_t)iv1.x * DD],      v05 = fcol[(size_t)iv1.y * DD];
        float v06 = fcol[(size_t)iv1.z * DD],      v07 = fcol[(size_t)iv1.w * DD];
        float v10 = fcol[(size_t)iv0.x * DD + 16], v11 = fcol[(size_t)iv0.y * DD + 16];
        float v12 = fcol[(size_t)iv0.z * DD + 16], v13 = fcol[(size_t)iv0.w * DD + 16];
        float v14 = fcol[(size_t)iv1.x * DD + 16], v15 = fcol[(size_t)iv1.y * DD + 16];
        float v16 = fcol[(size_t)iv1.z * DD + 16], v17 = fcol[(size_t)iv1.w * DD + 16];

        // next W tile generated while the A loads are in flight
        if (c + 1 < c1) WGEN(c + 1, cur ^ 1);

        union U { unsigned int u[4]; short8v v; } H0, L0, H1, L1;
        PKPAIR(v00, v01, H0.u[0], L0.u[0]);
        PKPAIR(v02, v03, H0.u[1], L0.u[1]);
        PKPAIR(v04, v05, H0.u[2], L0.u[2]);
        PKPAIR(v06, v07, H0.u[3], L0.u[3]);
        PKPAIR(v10, v11, H1.u[0], L1.u[0]);
        PKPAIR(v12, v13, H1.u[1], L1.u[1]);
        PKPAIR(v14, v15, H1.u[2], L1.u[2]);
        PKPAIR(v16, v17, H1.u[3], L1.u[3]);
        short8v cah0 = H0.v, cal0 = L0.v, cah1 = H1.v, cal1 = L1.v;

#pragma unroll
        for (int ni = 0; ni < 6; ++ni) {
            short8v bv = *(const short8v*)&sW[cur][ni * 16 + lr][kg * 8];
            acc[0][ni] = __builtin_amdgcn_mfma_f32_16x16x32_bf16(cah0, bv, acc[0][ni], 0, 0, 0);
            acc[1][ni] = __builtin_amdgcn_mfma_f32_16x16x32_bf16(cah1, bv, acc[1][ni], 0, 0, 0);
            acc[0][ni] = __builtin_amdgcn_mfma_f32_16x16x32_bf16(cal0, bv, acc[0][ni], 0, 0, 0);
            acc[1][ni] = __builtin_amdgcn_mfma_f32_16x16x32_bf16(cal1, bv, acc[1][ni], 0, 0, 0);
        }
        __syncthreads();
        cur ^= 1;
    }

    // nt epilogue (R8-validated form)
#pragma unroll
    for (int mi = 0; mi < 2; ++mi)
#pragma unroll
        for (int ni = 0; ni < 6; ++ni) {
            const int d0 = wvid * 32 + mi * 16 + kg * 4;
            const int x  = ni * 16 + lr;
            float* op = out + (((size_t)b * DD + d0) * GG + y) * GG + x;
#pragma unroll
            for (int r = 0; r < 4; ++r)
                __builtin_nontemporal_store(acc[mi][ni][r], op + (size_t)r * GG * GG);
        }
#undef WGEN
#undef PKPAIR
}

extern "C" void kernel_launch(void* const* d_in, const int* in_sizes, int n_in,
                              void* d_out, int out_size, void* d_ws, size_t ws_size,
                              hipStream_t stream) {
    const float* feat = (const float*)d_in[0];
    const float* pos  = (const float*)d_in[1];
    const float* lsig = (const float*)d_in[4];

    const int N  = in_sizes[2];                        // 4096
    const int B  = out_size / (DD * GG * GG);          // 8
    const int n_per = N / B;                           // 512 (== NPER)

    splat_all<<<B * GG, 256, 0, stream>>>(feat, pos, lsig, (float*)d_out, N, n_per);
}

// Round 15
// 23.840 us; speedup vs baseline: 1.3456x; 1.1010x over previous
//
#include <hip/hip_runtime.h>
#include <hip/hip_bf16.h>

#define GG    96     // grid size
#define DD    128    // feature dim
#define KC    32     // K-chunk = MFMA K
#define APAD  40     // padded LDS row stride in ushorts (80 B)
#define RCUT  18     // gaussian support radius in rows (exp(-18^2/32)=4e-5; validated)
#define NWIN  18     // normalizer-sum window radius (same cutoff scale)
#define NPER  512    // nodes per batch (N/B)

typedef __attribute__((ext_vector_type(8))) short short8v;  // 8 bf16 = 4 VGPRs
typedef __attribute__((ext_vector_type(4))) float f32x4;    // MFMA acc

// Single fused kernel (R14-validated structure): each (b,y) block self-sufficient.
//  (a) ballot counting-sort of its batch by floor(py)
//  (b) windowed normalizers (py,px,g) for its ragged K-band
//  (c) MFMA K-loop: W on the fly; A gathered from f, single bf16 (no hi/lo split:
//      error bound Σw·eps ~ 4e-4 since peak w ≈ 1/(2πσ²) ≈ 0.01)
__global__ __launch_bounds__(256, 3) void splat_all(
    const float* __restrict__ f, const float* __restrict__ pos,
    const float* __restrict__ log_sigma, float* __restrict__ out,
    int Nn, int n_per)
{
    // XCD-chunked swizzle: XCD x owns batch x (y-major within batch).
    const int swz = ((int)blockIdx.x % 8) * GG + (int)blockIdx.x / 8;
    const int b = swz / GG;
    const int y = swz % GG;
    const int tid = (int)threadIdx.x;
    const int lane = tid & 63;
    const int wvid = tid >> 6;
    const int lr = lane & 15;
    const int kg = lane >> 4;
    const int kpw = tid & 15;                 // fixed k-pair per thread
    const int nbase = b * NPER;
    const float yf = (float)y;

    __shared__ int ghist[8][GG];
    __shared__ int gpart[8][GG];
    __shared__ int spre[GG + 1];
    __shared__ int inv[NPER];
    __shared__ int wtot;
    __shared__ float spy_s[NPER], spx_s[NPER], sg_s[NPER];
    __shared__ float tSy[NPER], tSx[NPER];
    __shared__ __align__(16) unsigned short sW[2][GG][APAD];  // 15 KiB dbuf

    // ---- (a) in-LDS counting sort of the batch ----
    for (int i = tid; i < 8 * GG; i += 256) (&ghist[0][0])[i] = 0;
    __syncthreads();

    int binA, binB;
    {
        float pyA = pos[(size_t)(nbase + tid) * 2];
        float pyB = pos[(size_t)(nbase + tid + 256) * 2];
        binA = (int)floorf(pyA); binA = binA < 0 ? 0 : (binA > GG - 1 ? GG - 1 : binA);
        binB = (int)floorf(pyB); binB = binB < 0 ? 0 : (binB > GG - 1 ? GG - 1 : binB);
        atomicAdd(&ghist[wvid][binA], 1);
        atomicAdd(&ghist[4 + wvid][binB], 1);
    }
    const unsigned long long below = (lane == 0) ? 0ull : (~0ull >> (64 - lane));
    unsigned long long mA = ~0ull, mB = ~0ull;
#pragma unroll
    for (int bit = 0; bit < 7; ++bit) {
        unsigned long long bA = __ballot((binA >> bit) & 1);
        unsigned long long bB = __ballot((binB >> bit) & 1);
        mA &= ((binA >> bit) & 1) ? bA : ~bA;
        mB &= ((binB >> bit) & 1) ? bB : ~bB;
    }
    const int rA = __popcll(mA & below);
    const int rB = __popcll(mB & below);
    __syncthreads();

    int bc = 0;
    if (tid < GG) {
        int s = 0;
#pragma unroll
        for (int g = 0; g < 8; ++g) { gpart[g][tid] = s; s += ghist[g][tid]; }
        bc = s;
    }
    int xs = bc;
#pragma unroll
    for (int off = 1; off < 64; off <<= 1) {
        int v = __shfl_up(xs, off, 64);
        if (lane >= off) xs += v;
    }
    if (tid == 63) wtot = xs;
    __syncthreads();
    if (tid >= 64 && tid < GG) xs += wtot;
    if (tid < GG) spre[tid + 1] = xs;
    if (tid == 0) spre[0] = 0;
    __syncthreads();

    inv[spre[binA] + gpart[wvid][binA] + rA]     = tid;
    inv[spre[binB] + gpart[4 + wvid][binB] + rB] = tid + 256;
    __syncthreads();

    // ---- ragged K-band: chunks start exactly at klo (clamped to fit) ----
    const int lob = y - RCUT < 0 ? 0 : y - RCUT;
    const int hib = y + RCUT > GG ? GG : y + RCUT;
    const int klo = spre[lob];
    const int khi = spre[hib];
    const int nch = (khi - klo + KC - 1) >> 5;
    int j0 = klo;
    if (j0 + nch * KC > NPER) j0 = NPER - nch * KC;
    const int nbw = nch * KC;

    // ---- (b) per-node (py,px,g) for the band ----
    for (int i = tid; i < nbw; i += 256) {
        int j = j0 + i, nl = inv[j];
        spy_s[j] = pos[(size_t)(nbase + nl) * 2 + 0];
        spx_s[j] = pos[(size_t)(nbase + nl) * 2 + 1];
    }
    __syncthreads();

    const float sig = expf(log_sigma[0]);
    const float inv2s2 = 1.0f / (2.0f * sig * sig);

    for (int i = tid; i < 2 * nbw; i += 256) {
        int j = j0 + (i >> 1);
        float p = (i & 1) ? spx_s[j] : spy_s[j];
        int fp = (int)floorf(p);
        int w0 = fp - (NWIN - 1); if (w0 < 0) w0 = 0;
        int w1 = fp + NWIN;       if (w1 > GG - 1) w1 = GG - 1;
        float s = 0.f;
        for (int yy = w0; yy <= w1; ++yy) {
            float d = (float)yy - p;
            s += __expf(-d * d * inv2s2);
        }
        if (i & 1) tSx[j] = s; else tSy[j] = s;
    }
    __syncthreads();
    for (int i = tid; i < nbw; i += 256) {
        int j = j0 + i;
        sg_s[j] = 1.0f / (tSy[j] * tSx[j] + 1e-8f);
    }
    __syncthreads();

    // ---- (c) K-loop ----
    f32x4 acc[2][6];
#pragma unroll
    for (int mi = 0; mi < 2; ++mi)
#pragma unroll
        for (int ni = 0; ni < 6; ++ni) acc[mi][ni] = (f32x4){0.f, 0.f, 0.f, 0.f};

    const int ar0 = wvid * 32 + lr;
    const float* fcol = f + (size_t)nbase * DD + ar0;   // + nl*DD (+16 for row2)

#define WGEN(CC, BUF)                                                              \
    {                                                                              \
        const int j0_ = j0 + (CC) * KC + 2 * kpw;                                  \
        const float py0_ = spy_s[j0_], py1_ = spy_s[j0_ + 1];                      \
        const float px0_ = spx_s[j0_], px1_ = spx_s[j0_ + 1];                      \
        const float g0_ = sg_s[j0_],  g1_ = sg_s[j0_ + 1];                         \
        const float dy0_ = yf - py0_, dy1_ = yf - py1_;                            \
        const float ey0_ = __expf(-dy0_ * dy0_ * inv2s2) * g0_;                    \
        const float ey1_ = __expf(-dy1_ * dy1_ * inv2s2) * g1_;                    \
        _Pragma("unroll")                                                          \
        for (int i_ = 0; i_ < 6; ++i_) {                                           \
            int x_  = (tid + 256 * i_) >> 4;                                       \
            float xf_ = (float)x_;                                                 \
            float dx0_ = xf_ - px0_, dx1_ = xf_ - px1_;                            \
            float w0_ = ey0_ * __expf(-dx0_ * dx0_ * inv2s2);                      \
            float w1_ = ey1_ * __expf(-dx1_ * dx1_ * inv2s2);                      \
            __hip_bfloat162 bb_ = __float22bfloat162_rn(make_float2(w0_, w1_));    \
            *(unsigned int*)&sW[BUF][x_][2 * kpw] = *(unsigned int*)&bb_;          \
        }                                                                          \
    }

// pack pair (x0,x1) -> one u32 of 2 bf16 (RNE)
#define PKHI(X0, X1, HI)                                                           \
    {                                                                              \
        __hip_bfloat162 h_ = __float22bfloat162_rn(make_float2((X0), (X1)));       \
        __builtin_memcpy(&(HI), &h_, 4);                                           \
    }

    if (nch > 0) WGEN(0, 0);
    __syncthreads();

    int cur = 0;
    for (int c = 0; c < nch; ++c) {
        // A gather: orig node ids for my kg's 8 k's, then 16 direct f32 loads.
        // Lanes lr=0..15 read consecutive d -> full 64B segments (L2-hot).
        int4 iv0 = *(const int4*)&inv[j0 + c * KC + kg * 8];
        int4 iv1 = *(const int4*)&inv[j0 + c * KC + kg * 8 + 4];
        float v00 = fcol[(size_t)iv0.x * DD],      v01 = fcol[(size_t)iv0.y * DD];
        float v02 = fcol[(size_t)iv0.z * DD],      v03 = fcol[(size_t)iv0.w * DD];
        float v04 = fcol[(size_t)iv1.x * DD],      v05 = fcol[(size_t)iv1.y * DD];
        float v06 = fcol[(size_t)iv1.z * DD],      v07 = fcol[(size_t)iv1.w * DD];
        float v10 = fcol[(size_t)iv0.x * DD + 16], v11 = fcol[(size_t)iv0.y * DD + 16];
        float v12 = fcol[(size_t)iv0.z * DD + 16], v13 = fcol[(size_t)iv0.w * DD + 16];
        float v14 = fcol[(size_t)iv1.x * DD + 16], v15 = fcol[(size_t)iv1.y * DD + 16];
        float v16 = fcol[(size_t)iv1.z * DD + 16], v17 = fcol[(size_t)iv1.w * DD + 16];

        // next W tile generated while the A loads are in flight
        if (c + 1 < nch) WGEN(c + 1, cur ^ 1);

        union U { unsigned int u[4]; short8v v; } H0, H1;
        PKHI(v00, v01, H0.u[0]);
        PKHI(v02, v03, H0.u[1]);
        PKHI(v04, v05, H0.u[2]);
        PKHI(v06, v07, H0.u[3]);
        PKHI(v10, v11, H1.u[0]);
        PKHI(v12, v13, H1.u[1]);
        PKHI(v14, v15, H1.u[2]);
        PKHI(v16, v17, H1.u[3]);
        short8v cah0 = H0.v, cah1 = H1.v;

#pragma unroll
        for (int ni = 0; ni < 6; ++ni) {
            short8v bv = *(const short8v*)&sW[cur][ni * 16 + lr][kg * 8];
            acc[0][ni] = __builtin_amdgcn_mfma_f32_16x16x32_bf16(cah0, bv, acc[0][ni], 0, 0, 0);
            acc[1][ni] = __builtin_amdgcn_mfma_f32_16x16x32_bf16(cah1, bv, acc[1][ni], 0, 0, 0);
        }
        __syncthreads();
        cur ^= 1;
    }

    // nt epilogue (R8-validated form)
#pragma unroll
    for (int mi = 0; mi < 2; ++mi)
#pragma unroll
        for (int ni = 0; ni < 6; ++ni) {
            const int d0 = wvid * 32 + mi * 16 + kg * 4;
            const int x  = ni * 16 + lr;
            float* op = out + (((size_t)b * DD + d0) * GG + y) * GG + x;
#pragma unroll
            for (int r = 0; r < 4; ++r)
                __builtin_nontemporal_store(acc[mi][ni][r], op + (size_t)r * GG * GG);
        }
#undef WGEN
#undef PKHI
}

extern "C" void kernel_launch(void* const* d_in, const int* in_sizes, int n_in,
                              void* d_out, int out_size, void* d_ws, size_t ws_size,
                              hipStream_t stream) {
    const float* feat = (const float*)d_in[0];
    const float* pos  = (const float*)d_in[1];
    const float* lsig = (const float*)d_in[4];

    const int N  = in_sizes[2];                        // 4096
    const int B  = out_size / (DD * GG * GG);          // 8
    const int n_per = N / B;                           // 512 (== NPER)

    splat_all<<<B * GG, 256, 0, stream>>>(feat, pos, lsig, (float*)d_out, N, n_per);
}

// Round 16
// 22.508 us; speedup vs baseline: 1.4252x; 1.0592x over previous
//
#include <hip/hip_runtime.h>
#include <hip/hip_bf16.h>

#define GG    96     // grid size
#define DD    128    // feature dim
#define KC    32     // K-chunk = MFMA K
#define APAD  40     // padded LDS row stride in ushorts (80 B)
#define RCUT  15     // band radius: tail bound ~1.2e-4 abs (RCUT18 measured zero-cost)
#define NWIN  18     // normalizer window radius (edge nodes only; interior = analytic)
#define NPER  512    // nodes per batch (N/B)

typedef __attribute__((ext_vector_type(8))) short short8v;  // 8 bf16 = 4 VGPRs
typedef __attribute__((ext_vector_type(4))) float f32x4;    // MFMA acc

// Single fused kernel (R15-validated structure): each (b,y) block self-sufficient.
//  (a) ballot counting-sort of its batch by floor(py)
//  (b) normalizers: analytic sigma*sqrt(2pi) for interior nodes (Poisson summation,
//      exact to fp32), windowed sum only for grid-edge nodes
//  (c) MFMA K-loop: W on the fly; A gathered from f, single bf16
__global__ __launch_bounds__(256, 3) void splat_all(
    const float* __restrict__ f, const float* __restrict__ pos,
    const float* __restrict__ log_sigma, float* __restrict__ out,
    int Nn, int n_per)
{
    // XCD-chunked swizzle: XCD x owns batch x (y-major within batch).
    const int swz = ((int)blockIdx.x % 8) * GG + (int)blockIdx.x / 8;
    const int b = swz / GG;
    const int y = swz % GG;
    const int tid = (int)threadIdx.x;
    const int lane = tid & 63;
    const int wvid = tid >> 6;
    const int lr = lane & 15;
    const int kg = lane >> 4;
    const int kpw = tid & 15;                 // fixed k-pair per thread
    const int nbase = b * NPER;
    const float yf = (float)y;

    __shared__ int ghist[8][GG];
    __shared__ int gpart[8][GG];
    __shared__ int spre[GG + 1];
    __shared__ int inv[NPER];
    __shared__ int wtot;
    __shared__ float spy_s[NPER], spx_s[NPER], sg_s[NPER];
    __shared__ float tSy[NPER], tSx[NPER];
    __shared__ __align__(16) unsigned short sW[2][GG][APAD];  // 15 KiB dbuf

    // ---- (a) in-LDS counting sort of the batch ----
    for (int i = tid; i < 8 * GG; i += 256) (&ghist[0][0])[i] = 0;
    __syncthreads();

    int binA, binB;
    {
        float pyA = pos[(size_t)(nbase + tid) * 2];
        float pyB = pos[(size_t)(nbase + tid + 256) * 2];
        binA = (int)floorf(pyA); binA = binA < 0 ? 0 : (binA > GG - 1 ? GG - 1 : binA);
        binB = (int)floorf(pyB); binB = binB < 0 ? 0 : (binB > GG - 1 ? GG - 1 : binB);
        atomicAdd(&ghist[wvid][binA], 1);
        atomicAdd(&ghist[4 + wvid][binB], 1);
    }
    const unsigned long long below = (lane == 0) ? 0ull : (~0ull >> (64 - lane));
    unsigned long long mA = ~0ull, mB = ~0ull;
#pragma unroll
    for (int bit = 0; bit < 7; ++bit) {
        unsigned long long bA = __ballot((binA >> bit) & 1);
        unsigned long long bB = __ballot((binB >> bit) & 1);
        mA &= ((binA >> bit) & 1) ? bA : ~bA;
        mB &= ((binB >> bit) & 1) ? bB : ~bB;
    }
    const int rA = __popcll(mA & below);
    const int rB = __popcll(mB & below);
    __syncthreads();

    int bc = 0;
    if (tid < GG) {
        int s = 0;
#pragma unroll
        for (int g = 0; g < 8; ++g) { gpart[g][tid] = s; s += ghist[g][tid]; }
        bc = s;
    }
    int xs = bc;
#pragma unroll
    for (int off = 1; off < 64; off <<= 1) {
        int v = __shfl_up(xs, off, 64);
        if (lane >= off) xs += v;
    }
    if (tid == 63) wtot = xs;
    __syncthreads();
    if (tid >= 64 && tid < GG) xs += wtot;
    if (tid < GG) spre[tid + 1] = xs;
    if (tid == 0) spre[0] = 0;
    __syncthreads();

    inv[spre[binA] + gpart[wvid][binA] + rA]     = tid;
    inv[spre[binB] + gpart[4 + wvid][binB] + rB] = tid + 256;
    __syncthreads();

    // ---- ragged K-band: chunks start exactly at klo (clamped to fit) ----
    const int lob = y - RCUT < 0 ? 0 : y - RCUT;
    const int hib = y + RCUT > GG ? GG : y + RCUT;
    const int klo = spre[lob];
    const int khi = spre[hib];
    const int nch = (khi - klo + KC - 1) >> 5;
    int j0 = klo;
    if (j0 + nch * KC > NPER) j0 = NPER - nch * KC;
    const int nbw = nch * KC;

    // ---- (b) per-node (py,px,g) for the band ----
    for (int i = tid; i < nbw; i += 256) {
        int j = j0 + i, nl = inv[j];
        spy_s[j] = pos[(size_t)(nbase + nl) * 2 + 0];
        spx_s[j] = pos[(size_t)(nbase + nl) * 2 + 1];
    }
    __syncthreads();

    const float sig = expf(log_sigma[0]);
    const float inv2s2 = 1.0f / (2.0f * sig * sig);
    const float sfull = sig * 2.50662827463f;   // sigma*sqrt(2*pi): exact Z-sum (Poisson)

    for (int i = tid; i < 2 * nbw; i += 256) {
        int j = j0 + (i >> 1);
        float p = (i & 1) ? spx_s[j] : spy_s[j];
        int fp = (int)floorf(p);
        int w0 = fp - (NWIN - 1);
        int w1 = fp + NWIN;
        float s;
        if (w0 >= 0 && w1 <= GG - 1) {
            s = sfull;              // interior: window unclamped -> analytic sum
        } else {
            if (w0 < 0) w0 = 0;
            if (w1 > GG - 1) w1 = GG - 1;
            s = 0.f;
            for (int yy = w0; yy <= w1; ++yy) {
                float d = (float)yy - p;
                s += __expf(-d * d * inv2s2);
            }
        }
        if (i & 1) tSx[j] = s; else tSy[j] = s;
    }
    __syncthreads();
    for (int i = tid; i < nbw; i += 256) {
        int j = j0 + i;
        sg_s[j] = 1.0f / (tSy[j] * tSx[j] + 1e-8f);
    }
    __syncthreads();

    // ---- (c) K-loop ----
    f32x4 acc[2][6];
#pragma unroll
    for (int mi = 0; mi < 2; ++mi)
#pragma unroll
        for (int ni = 0; ni < 6; ++ni) acc[mi][ni] = (f32x4){0.f, 0.f, 0.f, 0.f};

    const int ar0 = wvid * 32 + lr;
    const float* fcol = f + (size_t)nbase * DD + ar0;   // + nl*DD (+16 for row2)

#define WGEN(CC, BUF)                                                              \
    {                                                                              \
        const int j0_ = j0 + (CC) * KC + 2 * kpw;                                  \
        const float py0_ = spy_s[j0_], py1_ = spy_s[j0_ + 1];                      \
        const float px0_ = spx_s[j0_], px1_ = spx_s[j0_ + 1];                      \
        const float g0_ = sg_s[j0_],  g1_ = sg_s[j0_ + 1];                         \
        const float dy0_ = yf - py0_, dy1_ = yf - py1_;                            \
        const float ey0_ = __expf(-dy0_ * dy0_ * inv2s2) * g0_;                    \
        const float ey1_ = __expf(-dy1_ * dy1_ * inv2s2) * g1_;                    \
        _Pragma("unroll")                                                          \
        for (int i_ = 0; i_ < 6; ++i_) {                                           \
            int x_  = (tid + 256 * i_) >> 4;                                       \
            float xf_ = (float)x_;                                                 \
            float dx0_ = xf_ - px0_, dx1_ = xf_ - px1_;                            \
            float w0_ = ey0_ * __expf(-dx0_ * dx0_ * inv2s2);                      \
            float w1_ = ey1_ * __expf(-dx1_ * dx1_ * inv2s2);                      \
            __hip_bfloat162 bb_ = __float22bfloat162_rn(make_float2(w0_, w1_));    \
            *(unsigned int*)&sW[BUF][x_][2 * kpw] = *(unsigned int*)&bb_;          \
        }                                                                          \
    }

// pack pair (x0,x1) -> one u32 of 2 bf16 (RNE)
#define PKHI(X0, X1, HI)                                                           \
    {                                                                              \
        __hip_bfloat162 h_ = __float22bfloat162_rn(make_float2((X0), (X1)));       \
        __builtin_memcpy(&(HI), &h_, 4);                                           \
    }

    if (nch > 0) WGEN(0, 0);
    __syncthreads();

    int cur = 0;
    for (int c = 0; c < nch; ++c) {
        // A gather: orig node ids for my kg's 8 k's, then 16 direct f32 loads.
        // Lanes lr=0..15 read consecutive d -> full 64B segments (L2-hot).
        int4 iv0 = *(const int4*)&inv[j0 + c * KC + kg * 8];
        int4 iv1 = *(const int4*)&inv[j0 + c * KC + kg * 8 + 4];
        float v00 = fcol[(size_t)iv0.x * DD],      v01 = fcol[(size_t)iv0.y * DD];
        float v02 = fcol[(size_t)iv0.z * DD],      v03 = fcol[(size_t)iv0.w * DD];
        float v04 = fcol[(size_t)iv1.x * DD],      v05 = fcol[(size_t)iv1.y * DD];
        float v06 = fcol[(size_t)iv1.z * DD],      v07 = fcol[(size_t)iv1.w * DD];
        float v10 = fcol[(size_t)iv0.x * DD + 16], v11 = fcol[(size_t)iv0.y * DD + 16];
        float v12 = fcol[(size_t)iv0.z * DD + 16], v13 = fcol[(size_t)iv0.w * DD + 16];
        float v14 = fcol[(size_t)iv1.x * DD + 16], v15 = fcol[(size_t)iv1.y * DD + 16];
        float v16 = fcol[(size_t)iv1.z * DD + 16], v17 = fcol[(size_t)iv1.w * DD + 16];

        // next W tile generated while the A loads are in flight
        if (c + 1 < nch) WGEN(c + 1, cur ^ 1);

        union U { unsigned int u[4]; short8v v; } H0, H1;
        PKHI(v00, v01, H0.u[0]);
        PKHI(v02, v03, H0.u[1]);
        PKHI(v04, v05, H0.u[2]);
        PKHI(v06, v07, H0.u[3]);
        PKHI(v10, v11, H1.u[0]);
        PKHI(v12, v13, H1.u[1]);
        PKHI(v14, v15, H1.u[2]);
        PKHI(v16, v17, H1.u[3]);
        short8v cah0 = H0.v, cah1 = H1.v;

#pragma unroll
        for (int ni = 0; ni < 6; ++ni) {
            short8v bv = *(const short8v*)&sW[cur][ni * 16 + lr][kg * 8];
            acc[0][ni] = __builtin_amdgcn_mfma_f32_16x16x32_bf16(cah0, bv, acc[0][ni], 0, 0, 0);
            acc[1][ni] = __builtin_amdgcn_mfma_f32_16x16x32_bf16(cah1, bv, acc[1][ni], 0, 0, 0);
        }
        __syncthreads();
        cur ^= 1;
    }

    // nt epilogue (R8-validated form)
#pragma unroll
    for (int mi = 0; mi < 2; ++mi)
#pragma unroll
        for (int ni = 0; ni < 6; ++ni) {
            const int d0 = wvid * 32 + mi * 16 + kg * 4;
            const int x  = ni * 16 + lr;
            float* op = out + (((size_t)b * DD + d0) * GG + y) * GG + x;
#pragma unroll
            for (int r = 0; r < 4; ++r)
                __builtin_nontemporal_store(acc[mi][ni][r], op + (size_t)r * GG * GG);
        }
#undef WGEN
#undef PKHI
}

extern "C" void kernel_launch(void* const* d_in, const int* in_sizes, int n_in,
                              void* d_out, int out_size, void* d_ws, size_t ws_size,
                              hipStream_t stream) {
    const float* feat = (const float*)d_in[0];
    const float* pos  = (const float*)d_in[1];
    const float* lsig = (const float*)d_in[4];

    const int N  = in_sizes[2];                        // 4096
    const int B  = out_size / (DD * GG * GG);          // 8
    const int n_per = N / B;                           // 512 (== NPER)

    splat_all<<<B * GG, 256, 0, stream>>>(feat, pos, lsig, (float*)d_out, N, n_per);
}

// Round 17
// 22.499 us; speedup vs baseline: 1.4258x; 1.0004x over previous
//
#include <hip/hip_runtime.h>
#include <hip/hip_bf16.h>

#define GG    96     // grid size
#define DD    128    // feature dim
#define KC    32     // K-chunk = MFMA K
#define APAD  40     // padded LDS row stride in ushorts (80 B)
#define RCUT  13     // band radius: tail bound ~7e-4 worst-case; absmax bit-stable 21->18->15
#define NWIN  18     // normalizer window radius (edge nodes only; interior = analytic)
#define NPER  512    // nodes per batch (N/B)

typedef __attribute__((ext_vector_type(8))) short short8v;  // 8 bf16 = 4 VGPRs
typedef __attribute__((ext_vector_type(4))) float f32x4;    // MFMA acc

// Single fused kernel (R16-validated structure): each (b,y) block self-sufficient.
//  (a) ballot counting-sort of its batch by floor(py)
//  (b) normalizers: analytic sigma*sqrt(2pi) interior, windowed sum at grid edges
//  (c) MFMA K-loop: W on the fly; A gathered from f with chunk-ahead prefetch
__global__ __launch_bounds__(256, 3) void splat_all(
    const float* __restrict__ f, const float* __restrict__ pos,
    const float* __restrict__ log_sigma, float* __restrict__ out,
    int Nn, int n_per)
{
    // XCD-chunked swizzle: XCD x owns batch x (y-major within batch).
    const int swz = ((int)blockIdx.x % 8) * GG + (int)blockIdx.x / 8;
    const int b = swz / GG;
    const int y = swz % GG;
    const int tid = (int)threadIdx.x;
    const int lane = tid & 63;
    const int wvid = tid >> 6;
    const int lr = lane & 15;
    const int kg = lane >> 4;
    const int kpw = tid & 15;                 // fixed k-pair per thread
    const int nbase = b * NPER;
    const float yf = (float)y;

    __shared__ int ghist[8][GG];
    __shared__ int gpart[8][GG];
    __shared__ int spre[GG + 1];
    __shared__ int inv[NPER];
    __shared__ int wtot;
    __shared__ float spy_s[NPER], spx_s[NPER], sg_s[NPER];
    __shared__ float tSy[NPER], tSx[NPER];
    __shared__ __align__(16) unsigned short sW[2][GG][APAD];  // 15 KiB dbuf

    // ---- (a) in-LDS counting sort of the batch ----
    for (int i = tid; i < 8 * GG; i += 256) (&ghist[0][0])[i] = 0;
    __syncthreads();

    int binA, binB;
    {
        float pyA = pos[(size_t)(nbase + tid) * 2];
        float pyB = pos[(size_t)(nbase + tid + 256) * 2];
        binA = (int)floorf(pyA); binA = binA < 0 ? 0 : (binA > GG - 1 ? GG - 1 : binA);
        binB = (int)floorf(pyB); binB = binB < 0 ? 0 : (binB > GG - 1 ? GG - 1 : binB);
        atomicAdd(&ghist[wvid][binA], 1);
        atomicAdd(&ghist[4 + wvid][binB], 1);
    }
    const unsigned long long below = (lane == 0) ? 0ull : (~0ull >> (64 - lane));
    unsigned long long mA = ~0ull, mB = ~0ull;
#pragma unroll
    for (int bit = 0; bit < 7; ++bit) {
        unsigned long long bA = __ballot((binA >> bit) & 1);
        unsigned long long bB = __ballot((binB >> bit) & 1);
        mA &= ((binA >> bit) & 1) ? bA : ~bA;
        mB &= ((binB >> bit) & 1) ? bB : ~bB;
    }
    const int rA = __popcll(mA & below);
    const int rB = __popcll(mB & below);
    __syncthreads();

    int bc = 0;
    if (tid < GG) {
        int s = 0;
#pragma unroll
        for (int g = 0; g < 8; ++g) { gpart[g][tid] = s; s += ghist[g][tid]; }
        bc = s;
    }
    int xs = bc;
#pragma unroll
    for (int off = 1; off < 64; off <<= 1) {
        int v = __shfl_up(xs, off, 64);
        if (lane >= off) xs += v;
    }
    if (tid == 63) wtot = xs;
    __syncthreads();
    if (tid >= 64 && tid < GG) xs += wtot;
    if (tid < GG) spre[tid + 1] = xs;
    if (tid == 0) spre[0] = 0;
    __syncthreads();

    inv[spre[binA] + gpart[wvid][binA] + rA]     = tid;
    inv[spre[binB] + gpart[4 + wvid][binB] + rB] = tid + 256;
    __syncthreads();

    // ---- ragged K-band: chunks start exactly at klo (clamped to fit) ----
    const int lob = y - RCUT < 0 ? 0 : y - RCUT;
    const int hib = y + RCUT > GG ? GG : y + RCUT;
    const int klo = spre[lob];
    const int khi = spre[hib];
    const int nch = (khi - klo + KC - 1) >> 5;
    int j0 = klo;
    if (j0 + nch * KC > NPER) j0 = NPER - nch * KC;
    const int nbw = nch * KC;

    // ---- (b) per-node (py,px,g) for the band ----
    for (int i = tid; i < nbw; i += 256) {
        int j = j0 + i, nl = inv[j];
        spy_s[j] = pos[(size_t)(nbase + nl) * 2 + 0];
        spx_s[j] = pos[(size_t)(nbase + nl) * 2 + 1];
    }
    __syncthreads();

    const float sig = expf(log_sigma[0]);
    const float inv2s2 = 1.0f / (2.0f * sig * sig);
    const float sfull = sig * 2.50662827463f;   // sigma*sqrt(2*pi): exact Z-sum (Poisson)

    for (int i = tid; i < 2 * nbw; i += 256) {
        int j = j0 + (i >> 1);
        float p = (i & 1) ? spx_s[j] : spy_s[j];
        int fp = (int)floorf(p);
        int w0 = fp - (NWIN - 1);
        int w1 = fp + NWIN;
        float s;
        if (w0 >= 0 && w1 <= GG - 1) {
            s = sfull;              // interior: window unclamped -> analytic sum
        } else {
            if (w0 < 0) w0 = 0;
            if (w1 > GG - 1) w1 = GG - 1;
            s = 0.f;
            for (int yy = w0; yy <= w1; ++yy) {
                float d = (float)yy - p;
                s += __expf(-d * d * inv2s2);
            }
        }
        if (i & 1) tSx[j] = s; else tSy[j] = s;
    }
    __syncthreads();
    for (int i = tid; i < nbw; i += 256) {
        int j = j0 + i;
        sg_s[j] = 1.0f / (tSy[j] * tSx[j] + 1e-8f);
    }
    __syncthreads();

    // ---- (c) K-loop ----
    f32x4 acc[2][6];
#pragma unroll
    for (int mi = 0; mi < 2; ++mi)
#pragma unroll
        for (int ni = 0; ni < 6; ++ni) acc[mi][ni] = (f32x4){0.f, 0.f, 0.f, 0.f};

    const int ar0 = wvid * 32 + lr;
    const float* fcol = f + (size_t)nbase * DD + ar0;   // + nl*DD (+16 for row2)

#define WGEN(CC, BUF)                                                              \
    {                                                                              \
        const int j0_ = j0 + (CC) * KC + 2 * kpw;                                  \
        const float py0_ = spy_s[j0_], py1_ = spy_s[j0_ + 1];                      \
        const float px0_ = spx_s[j0_], px1_ = spx_s[j0_ + 1];                      \
        const float g0_ = sg_s[j0_],  g1_ = sg_s[j0_ + 1];                         \
        const float dy0_ = yf - py0_, dy1_ = yf - py1_;                            \
        const float ey0_ = __expf(-dy0_ * dy0_ * inv2s2) * g0_;                    \
        const float ey1_ = __expf(-dy1_ * dy1_ * inv2s2) * g1_;                    \
        _Pragma("unroll")                                                          \
        for (int i_ = 0; i_ < 6; ++i_) {                                           \
            int x_  = (tid + 256 * i_) >> 4;                                       \
            float xf_ = (float)x_;                                                 \
            float dx0_ = xf_ - px0_, dx1_ = xf_ - px1_;                            \
            float w0_ = ey0_ * __expf(-dx0_ * dx0_ * inv2s2);                      \
            float w1_ = ey1_ * __expf(-dx1_ * dx1_ * inv2s2);                      \
            __hip_bfloat162 bb_ = __float22bfloat162_rn(make_float2(w0_, w1_));    \
            *(unsigned int*)&sW[BUF][x_][2 * kpw] = *(unsigned int*)&bb_;          \
        }                                                                          \
    }

// issue the 16 A loads for chunk CC into named regs
#define LOADA(CC)                                                                  \
    {                                                                              \
        int4 iv0_ = *(const int4*)&inv[j0 + (CC) * KC + kg * 8];                   \
        int4 iv1_ = *(const int4*)&inv[j0 + (CC) * KC + kg * 8 + 4];               \
        v00 = fcol[(size_t)iv0_.x * DD];      v01 = fcol[(size_t)iv0_.y * DD];     \
        v02 = fcol[(size_t)iv0_.z * DD];      v03 = fcol[(size_t)iv0_.w * DD];     \
        v04 = fcol[(size_t)iv1_.x * DD];      v05 = fcol[(size_t)iv1_.y * DD];     \
        v06 = fcol[(size_t)iv1_.z * DD];      v07 = fcol[(size_t)iv1_.w * DD];     \
        v10 = fcol[(size_t)iv0_.x * DD + 16]; v11 = fcol[(size_t)iv0_.y * DD + 16];\
        v12 = fcol[(size_t)iv0_.z * DD + 16]; v13 = fcol[(size_t)iv0_.w * DD + 16];\
        v14 = fcol[(size_t)iv1_.x * DD + 16]; v15 = fcol[(size_t)iv1_.y * DD + 16];\
        v16 = fcol[(size_t)iv1_.z * DD + 16]; v17 = fcol[(size_t)iv1_.w * DD + 16];\
    }

// pack pair (x0,x1) -> one u32 of 2 bf16 (RNE)
#define PKHI(X0, X1, HI)                                                           \
    {                                                                              \
        __hip_bfloat162 h_ = __float22bfloat162_rn(make_float2((X0), (X1)));       \
        __builtin_memcpy(&(HI), &h_, 4);                                           \
    }

    float v00, v01, v02, v03, v04, v05, v06, v07;
    float v10, v11, v12, v13, v14, v15, v16, v17;

    if (nch > 0) {
        WGEN(0, 0);
        LOADA(0);            // chunk-0 A loads in flight across the barrier
    }
    __syncthreads();

    int cur = 0;
    for (int c = 0; c < nch; ++c) {
        // pack current chunk's A (loads issued last iteration / prologue)
        union U { unsigned int u[4]; short8v v; } H0, H1;
        PKHI(v00, v01, H0.u[0]);
        PKHI(v02, v03, H0.u[1]);
        PKHI(v04, v05, H0.u[2]);
        PKHI(v06, v07, H0.u[3]);
        PKHI(v10, v11, H1.u[0]);
        PKHI(v12, v13, H1.u[1]);
        PKHI(v14, v15, H1.u[2]);
        PKHI(v16, v17, H1.u[3]);
        short8v cah0 = H0.v, cah1 = H1.v;

        // issue next chunk's A loads + generate next W tile (latency hides under MFMA)
        if (c + 1 < nch) {
            LOADA(c + 1);
            WGEN(c + 1, cur ^ 1);
        }

#pragma unroll
        for (int ni = 0; ni < 6; ++ni) {
            short8v bv = *(const short8v*)&sW[cur][ni * 16 + lr][kg * 8];
            acc[0][ni] = __builtin_amdgcn_mfma_f32_16x16x32_bf16(cah0, bv, acc[0][ni], 0, 0, 0);
            acc[1][ni] = __builtin_amdgcn_mfma_f32_16x16x32_bf16(cah1, bv, acc[1][ni], 0, 0, 0);
        }
        __syncthreads();
        cur ^= 1;
    }

    // nt epilogue (R8-validated form)
#pragma unroll
    for (int mi = 0; mi < 2; ++mi)
#pragma unroll
        for (int ni = 0; ni < 6; ++ni) {
            const int d0 = wvid * 32 + mi * 16 + kg * 4;
            const int x  = ni * 16 + lr;
            float* op = out + (((size_t)b * DD + d0) * GG + y) * GG + x;
#pragma unroll
            for (int r = 0; r < 4; ++r)
                __builtin_nontemporal_store(acc[mi][ni][r], op + (size_t)r * GG * GG);
        }
#undef WGEN
#undef LOADA
#undef PKHI
}

extern "C" void kernel_launch(void* const* d_in, const int* in_sizes, int n_in,
                              void* d_out, int out_size, void* d_ws, size_t ws_size,
                              hipStream_t stream) {
    const float* feat = (const float*)d_in[0];
    const float* pos  = (const float*)d_in[1];
    const float* lsig = (const float*)d_in[4];

    const int N  = in_sizes[2];                        // 4096
    const int B  = out_size / (DD * GG * GG);          // 8
    const int n_per = N / B;                           // 512 (== NPER)

    splat_all<<<B * GG, 256, 0, stream>>>(feat, pos, lsig, (float*)d_out, N, n_per);
}